// Round 2
// baseline (811.987 us; speedup 1.0000x reference)
//
#include <hip/hip_runtime.h>
#include <stdint.h>

// PQ soft-assignment layer, MI355X (gfx950).
// B=65536, feat=512, M=8, K=256, D=64.
// R1: same compute path as R0 (MFMA1 S^T = C*xhat^T -> in-register softmax ->
// shuffle relayout -> MFMA2), but ALL global stores now go through wave-private
// LDS staging so each store instruction writes contiguous, line-aligned 1024 B.
// R0's fragment-direct stores (16 scattered 64-B segments/instr) caused 3.7x
// write amplification (WRITE_SIZE 2.42 GB vs 671 MB data).

typedef float f32x4 __attribute__((ext_vector_type(4)));
typedef short s16x8 __attribute__((ext_vector_type(8)));
typedef unsigned short u16;

constexpr int MM = 8;     // groups
constexpr int KD = 256;   // codewords per group
constexpr int DD = 64;    // sub-dim

#define LGKM0() asm volatile("s_waitcnt lgkmcnt(0)" ::: "memory")

// float -> bf16 bits, round-to-nearest-even
__device__ __forceinline__ unsigned f2bf1(float f) {
  unsigned u = __float_as_uint(f);
  u += 0x7FFFu + ((u >> 16) & 1u);
  return u >> 16;
}
__device__ __forceinline__ unsigned packbf(float lo, float hi) {
  return f2bf1(lo) | (f2bf1(hi) << 16);
}

// Convert C (f32 [M][K][D]) into bf16 Cm [M][K][D] and CmT [M][D][K] in ws.
__global__ __launch_bounds__(256) void pq_prep(const float* __restrict__ C,
                                               u16* __restrict__ Cm,
                                               u16* __restrict__ Cmt) {
  int idx = blockIdx.x * 256 + threadIdx.x;
  if (idx >= MM * KD * DD) return;
  int d = idx & (DD - 1);
  int k = (idx >> 6) & (KD - 1);
  int m = idx >> 14;
  u16 v = (u16)f2bf1(C[idx]);
  Cm[idx] = v;
  Cmt[(m * DD + d) * KD + k] = v;
}

// Per-wave LDS staging buffer: 16 rows x 132 floats (128 data + 4 pad) = 8448 B.
// Pad makes the b128 write pattern 2-way bank aliasing (free, m136).
constexpr int SROW = 132;           // floats per staged row (codes half)
constexpr int SROW_X = 68;          // floats per staged row (xhat)
constexpr int SWAVE = 16 * SROW;    // 2112 floats per wave

__global__ __launch_bounds__(256) void pq_main(const float* __restrict__ x,
                                               const u16* __restrict__ Cm,
                                               const u16* __restrict__ Cmt,
                                               float* __restrict__ xhat,
                                               float* __restrict__ codes) {
  __shared__ float sbuf[4 * SWAVE];   // 33792 B -> 4 blocks/CU

  const int tid = threadIdx.x;
  const int lane = tid & 63;
  const int wave = tid >> 6;   // 0..3
  const int c = lane & 15;     // frag col / this lane's b-column
  const int g = lane >> 4;     // 0..3 lane group
  const int m = blockIdx.x & 7;
  const int b0 = (blockIdx.x >> 3) * 64;
  const int brow = b0 + wave * 16 + c;   // this lane's b row

  float* sb = sbuf + wave * SWAVE;      // wave-private

  // ---------------- load x slice, L2-normalize, build xhat B-frags ----------
  // B-operand layout (16x16x32): col = lane&15 (=b), k(=d) = g*8 + i
  const float* xp = x + (size_t)brow * (MM * DD) + m * DD;
  f32x4 xv[4];
#pragma unroll
  for (int kf = 0; kf < 2; ++kf) {
    const f32x4* p = (const f32x4*)(xp + kf * 32 + g * 8);
    xv[kf * 2 + 0] = p[0];
    xv[kf * 2 + 1] = p[1];
  }
  float ssq = 0.f;
#pragma unroll
  for (int t = 0; t < 4; ++t)
    ssq += xv[t].x * xv[t].x + xv[t].y * xv[t].y + xv[t].z * xv[t].z + xv[t].w * xv[t].w;
  ssq += __shfl_xor(ssq, 16);
  ssq += __shfl_xor(ssq, 32);
  const float inv = 1.0f / fmaxf(sqrtf(ssq), 1e-12f);

  s16x8 bx[2];
#pragma unroll
  for (int kf = 0; kf < 2; ++kf) {
    union { s16x8 v; unsigned u[4]; } un;
#pragma unroll
    for (int t = 0; t < 2; ++t) {
      f32x4 q = xv[kf * 2 + t];
      un.u[t * 2 + 0] = packbf(q.x * inv, q.y * inv);
      un.u[t * 2 + 1] = packbf(q.z * inv, q.w * inv);
    }
    bx[kf] = un.v;
  }

  // ---------------- MFMA1: S^T[k][b] = sum_d C[k][d] * xhat[b][d] -----------
  // A-frag (C): row(=k within frag) = c, d = kf*32 + g*8 + i  -> contiguous.
  // acc[rf]: value = ips[b=brow][k = rf*16 + 4*g + reg]
  f32x4 acc[16];
#pragma unroll
  for (int rf = 0; rf < 16; ++rf) acc[rf] = (f32x4){0.f, 0.f, 0.f, 0.f};

  const u16* cmp = Cm + ((size_t)m * KD + c) * DD + g * 8;
#pragma unroll 4
  for (int rf = 0; rf < 16; ++rf) {
#pragma unroll
    for (int kf = 0; kf < 2; ++kf) {
      s16x8 A = *(const s16x8*)(cmp + rf * 16 * DD + kf * 32);
      acc[rf] = __builtin_amdgcn_mfma_f32_16x16x32_bf16(A, bx[kf], acc[rf], 0, 0, 0);
    }
  }

  // ---------------- softmax over k (fully lane-local + 2 shuffles) ----------
  float mx = -3.0e38f;
#pragma unroll
  for (int rf = 0; rf < 16; ++rf)
    mx = fmaxf(mx, fmaxf(fmaxf(acc[rf].x, acc[rf].y), fmaxf(acc[rf].z, acc[rf].w)));
  mx = fmaxf(mx, __shfl_xor(mx, 16));
  mx = fmaxf(mx, __shfl_xor(mx, 32));

  float sum = 0.f;
#pragma unroll
  for (int rf = 0; rf < 16; ++rf) {
    acc[rf].x = __expf(acc[rf].x - mx);
    acc[rf].y = __expf(acc[rf].y - mx);
    acc[rf].z = __expf(acc[rf].z - mx);
    acc[rf].w = __expf(acc[rf].w - mx);
    sum += acc[rf].x + acc[rf].y + acc[rf].z + acc[rf].w;
  }
  sum += __shfl_xor(sum, 16);
  sum += __shfl_xor(sum, 32);
  const float rs = 1.0f / sum;
#pragma unroll
  for (int rf = 0; rf < 16; ++rf) {
    acc[rf].x *= rs; acc[rf].y *= rs; acc[rf].z *= rs; acc[rf].w *= rs;
  }

  // ---------------- store codes via LDS transpose (two k-halves) ------------
  // Stage frag layout [row c][k], read back row-major: each store instruction
  // writes 2 rows x 512 B contiguous (full lines).
  const int rl = lane >> 5;   // 0..1: row within pair
  const int cl = lane & 31;   // 32 x 16B chunks = 512 B half-row
#pragma unroll
  for (int h = 0; h < 2; ++h) {
    LGKM0();  // WAR: previous half's reads must be consumed before overwrite
#pragma unroll
    for (int rf = 0; rf < 8; ++rf)
      *(f32x4*)(sb + c * SROW + rf * 16 + 4 * g) = acc[h * 8 + rf];
    LGKM0();
#pragma unroll
    for (int t = 0; t < 8; ++t) {
      int row = 2 * t + rl;
      f32x4 v = *(const f32x4*)(sb + row * SROW + cl * 4);
      *(f32x4*)(codes + ((size_t)(b0 + wave * 16 + row) * MM + m) * KD + h * 128 + cl * 4) = v;
    }
  }

  // ---------------- build P^T B-frags via register shuffles -----------------
  // Need B[k][col=b]: lane (c,g) holds k = kf*32 + 8g + i for its own b(=c col).
  // Source regs hold k = rf*16 + 4*g_src + r. For target (c,g):
  //   elems 0..3 from lane (c, 2*(g&1)), elems 4..7 from lane (c, 2*(g&1)+1),
  //   rf = 2*kf + (g>>1).
  unsigned w0[16], w1[16];
#pragma unroll
  for (int rf = 0; rf < 16; ++rf) {
    w0[rf] = packbf(acc[rf].x, acc[rf].y);
    w1[rf] = packbf(acc[rf].z, acc[rf].w);
  }
  const int laneA = c + 32 * (g & 1);
  const int laneB = laneA + 16;
  const bool hi = (g >> 1) != 0;
  s16x8 Bp[8];
#pragma unroll
  for (int kf = 0; kf < 8; ++kf) {
    unsigned a0e = __shfl(w0[2 * kf], laneA);
    unsigned a1e = __shfl(w1[2 * kf], laneA);
    unsigned a0o = __shfl(w0[2 * kf + 1], laneA);
    unsigned a1o = __shfl(w1[2 * kf + 1], laneA);
    unsigned b0e = __shfl(w0[2 * kf], laneB);
    unsigned b1e = __shfl(w1[2 * kf], laneB);
    unsigned b0o = __shfl(w0[2 * kf + 1], laneB);
    unsigned b1o = __shfl(w1[2 * kf + 1], laneB);
    union { s16x8 v; unsigned u[4]; } un;
    un.u[0] = hi ? a0o : a0e;
    un.u[1] = hi ? a1o : a1e;
    un.u[2] = hi ? b0o : b0e;
    un.u[3] = hi ? b1o : b1e;
    Bp[kf] = un.v;
  }

  // ---------------- MFMA2: xhat^T[d][b] = sum_k C[k][d] * p[b][k] -----------
  // A-frag (C^T): row(=d) = c, k = kf*32 + g*8 + i -> contiguous in CmT.
  f32x4 acc2[4];
#pragma unroll
  for (int rf = 0; rf < 4; ++rf) acc2[rf] = (f32x4){0.f, 0.f, 0.f, 0.f};

  const u16* ctp = Cmt + ((size_t)m * DD + c) * KD + g * 8;
#pragma unroll 2
  for (int rf2 = 0; rf2 < 4; ++rf2) {
#pragma unroll
    for (int kf = 0; kf < 8; ++kf) {
      s16x8 A = *(const s16x8*)(ctp + rf2 * 16 * KD + kf * 32);
      acc2[rf2] = __builtin_amdgcn_mfma_f32_16x16x32_bf16(A, Bp[kf], acc2[rf2], 0, 0, 0);
    }
  }

  // ---------------- store x_hat via LDS transpose ---------------------------
  // Each store instruction writes 4 rows x 256 B contiguous (full lines).
  LGKM0();  // WAR vs codes reads
#pragma unroll
  for (int rf2 = 0; rf2 < 4; ++rf2)
    *(f32x4*)(sb + c * SROW_X + rf2 * 16 + 4 * g) = acc2[rf2];
  LGKM0();
  const int rl2 = lane >> 4;   // 0..3 row within quad
  const int cl2 = lane & 15;   // 16 x 16B chunks = 256 B row slice
#pragma unroll
  for (int t = 0; t < 4; ++t) {
    int row = 4 * t + rl2;
    f32x4 v = *(const f32x4*)(sb + row * SROW_X + cl2 * 4);
    *(f32x4*)(xhat + (size_t)(b0 + wave * 16 + row) * (MM * DD) + m * DD + cl2 * 4) = v;
  }
}

extern "C" void kernel_launch(void* const* d_in, const int* in_sizes, int n_in,
                              void* d_out, int out_size, void* d_ws, size_t ws_size,
                              hipStream_t stream) {
  const float* x = (const float*)d_in[0];
  const float* C = (const float*)d_in[1];
  const int B = in_sizes[0] / (MM * DD);   // 65536

  float* xhat = (float*)d_out;
  float* codes = (float*)d_out + (size_t)B * MM * DD;

  u16* Cm = (u16*)d_ws;
  u16* Cmt = Cm + MM * KD * DD;   // 512 KB total in ws

  pq_prep<<<(MM * KD * DD + 255) / 256, 256, 0, stream>>>(C, Cm, Cmt);
  pq_main<<<(B / 64) * MM, 256, 0, stream>>>(x, Cm, Cmt, xhat, codes);
}